// Round 7
// baseline (890.346 us; speedup 1.0000x reference)
//
#include <hip/hip_runtime.h>
#include <hip/hip_bf16.h>
#include <cstdint>

#define NV 20000
#define NE 40000
#define NODE_IN 74
#define EDGE_IN 12
#define D 64
#define EHID 128
#define NSTEPS 6

typedef __bf16 bf16x8 __attribute__((ext_vector_type(8)));
typedef float f32x4 __attribute__((ext_vector_type(4)));

// ---------------- node projection: h = relu(nf @ Wp^T + bp); also zero neigh ----------------
__global__ __launch_bounds__(256) void k_proj(const float* __restrict__ nf,
                                              const float* __restrict__ W,
                                              const float* __restrict__ b,
                                              float* __restrict__ h,
                                              float* __restrict__ neigh) {
  __shared__ float sn[4][NODE_IN];
  int tid = threadIdx.x;
  int nb = blockIdx.x * 4;
  for (int idx = tid; idx < 4 * NODE_IN; idx += 256) {
    int r = idx / NODE_IN, c = idx % NODE_IN;
    sn[r][c] = nf[(size_t)(nb + r) * NODE_IN + c];
  }
  __syncthreads();
  int nl = tid >> 6, o = tid & 63;
  float acc = b[o];
#pragma unroll
  for (int i = 0; i < NODE_IN; ++i) acc = fmaf(sn[nl][i], W[o * NODE_IN + i], acc);
  h[(size_t)(nb + nl) * D + o] = fmaxf(acc, 0.f);
  neigh[(size_t)(nb + nl) * D + o] = 0.f;
}

// ------------- edge net layer 1: t = relu(ef @ W1^T + b1), bf16 -------------
__global__ __launch_bounds__(256) void k_edge1(const float* __restrict__ ef,
                                               const float* __restrict__ W1,
                                               const float* __restrict__ b1,
                                               __hip_bfloat16* __restrict__ t_bf) {
  __shared__ float se[2][EDGE_IN];
  int tid = threadIdx.x;
  int eb = blockIdx.x * 2;
  if (tid < 2 * EDGE_IN)
    se[tid / EDGE_IN][tid % EDGE_IN] =
        ef[(size_t)(eb + tid / EDGE_IN) * EDGE_IN + tid % EDGE_IN];
  __syncthreads();
  int el = tid >> 7, k = tid & 127;
  float acc = b1[k];
#pragma unroll
  for (int j = 0; j < EDGE_IN; ++j) acc = fmaf(se[el][j], W1[k * EDGE_IN + j], acc);
  t_bf[(size_t)(eb + el) * EHID + k] = __float2bfloat16(fmaxf(acc, 0.f));
}

// ---------------- W2 fp32 -> bf16 ----------------
__global__ __launch_bounds__(256) void k_cvt_w2(const float* __restrict__ W2,
                                                __hip_bfloat16* __restrict__ w2b) {
  int idx = blockIdx.x * 256 + threadIdx.x;
  if (idx < D * D * EHID) w2b[idx] = __float2bfloat16(W2[idx]);
}

// ------- build GRU B matrix (256 x 128), hi/lo bf16 split -------
__global__ __launch_bounds__(256) void k_build_b(const float* __restrict__ Wih,
                                                 const float* __restrict__ Whh,
                                                 __hip_bfloat16* __restrict__ Bhi,
                                                 __hip_bfloat16* __restrict__ Blo) {
  int idx = blockIdx.x * 256 + threadIdx.x;  // 32768 total
  int n = idx >> 7, k = idx & 127;
  int o = n & 63, cls = n >> 6;
  float v;
  if (cls == 0)      v = (k < 64) ? Wih[o * 64 + k]         : Whh[o * 64 + (k - 64)];
  else if (cls == 1) v = (k < 64) ? Wih[(64 + o) * 64 + k]  : Whh[(64 + o) * 64 + (k - 64)];
  else if (cls == 2) v = (k < 64) ? Wih[(128 + o) * 64 + k] : 0.f;
  else               v = (k < 64) ? 0.f                     : Whh[(128 + o) * 64 + (k - 64)];
  __hip_bfloat16 hi = __float2bfloat16(v);
  Bhi[idx] = hi;
  Blo[idx] = __float2bfloat16(v - __bfloat162float(hi));
}

// ------- fused NNConv message+aggregate, L1-shared W2, barrier-free loop -------
// Grid: ceil(NE/256) * 4. Block (eblk, cg): 256 edges, cols [cg*16, cg*16+16).
// ALL 4 waves read the SAME 4 KB W2 slice per i (wave 0 misses to L2, waves 1-3
// hit L1) and split the 256 edges (wave = 64 edges). No __syncthreads in the
// i-loop; depth-2 prefetch in named regs (runtime-indexed arrays spill — R3).
#define HS_STRIDE 260   // f32 elems per HsT row (256 + 4), rows 16B-aligned
__global__ __launch_bounds__(256) void k_msg(const float* __restrict__ h,
                                             const __hip_bfloat16* __restrict__ t_bf,
                                             const __hip_bfloat16* __restrict__ w2,
                                             const float* __restrict__ b2,
                                             const int* __restrict__ src,
                                             const int* __restrict__ dst,
                                             float* __restrict__ neigh) {
  __shared__ __align__(16) float HsT[64 * HS_STRIDE];  // [i][edge] fp32, 66.6 KB
  __shared__ int Ss[256];
  __shared__ int Ds[256];
  int tid = threadIdx.x;
  int eblk = blockIdx.x >> 2, cg = blockIdx.x & 3;
  int e0 = eblk * 256;
  int rot = (blockIdx.x * 17) & 63;   // decorrelate W2 walk across blocks

  {
    int e = e0 + tid; if (e > NE - 1) e = NE - 1;
    Ss[tid] = src[e];
    Ds[tid] = dst[e];
  }
  __syncthreads();  // Ss ready
  // gather h[src] -> HsT[i][r]; lanes sweep i (coalesced 256B row reads)
  for (int idx = tid; idx < 256 * 64; idx += 256) {
    int r = idx >> 6, i = idx & 63;
    HsT[i * HS_STRIDE + r] = h[(size_t)Ss[r] * D + i];
  }

  int wave = tid >> 6, lane = tid & 63;
  int lr = lane & 15, lq = lane >> 4;
  const int ocol = cg * 16 + lr;

  // loop-invariant A-frags: this wave's 64 edges (4 M-tiles) x 4 k-steps
  bf16x8 tf[4][4];
#pragma unroll
  for (int mt = 0; mt < 4; ++mt) {
    int er = e0 + wave * 64 + mt * 16 + lr; if (er > NE - 1) er = NE - 1;
#pragma unroll
    for (int ks = 0; ks < 4; ++ks)
      tf[mt][ks] = *(const bf16x8*)(t_bf + (size_t)er * EHID + ks * 32 + lq * 8);
  }

  const __hip_bfloat16* wbase = w2 + (size_t)ocol * EHID + lq * 8;

  bf16x8 ba0, ba1, ba2, ba3, bb0, bb1, bb2, bb3;
  float b2a, b2b;

#define LDW2(BUF, B2V, IG) do {                                          \
    const __hip_bfloat16* wp_ = wbase + (size_t)(IG) * (64 * EHID);      \
    BUF##0 = *(const bf16x8*)(wp_);                                      \
    BUF##1 = *(const bf16x8*)(wp_ + 32);                                 \
    BUF##2 = *(const bf16x8*)(wp_ + 64);                                 \
    BUF##3 = *(const bf16x8*)(wp_ + 96);                                 \
    B2V = b2[(IG) * 64 + ocol];                                          \
  } while (0)

#define STEP(BUF, B2V, IG) do {                                          \
    _Pragma("unroll")                                                    \
    for (int mt = 0; mt < 4; ++mt) {                                     \
      f32x4 P = {B2V, B2V, B2V, B2V};                                    \
      P = __builtin_amdgcn_mfma_f32_16x16x32_bf16(tf[mt][0], BUF##0, P, 0, 0, 0); \
      P = __builtin_amdgcn_mfma_f32_16x16x32_bf16(tf[mt][1], BUF##1, P, 0, 0, 0); \
      P = __builtin_amdgcn_mfma_f32_16x16x32_bf16(tf[mt][2], BUF##2, P, 0, 0, 0); \
      P = __builtin_amdgcn_mfma_f32_16x16x32_bf16(tf[mt][3], BUF##3, P, 0, 0, 0); \
      f32x4 hf = *(const f32x4*)(HsT + (IG) * HS_STRIDE + wave * 64 + mt * 16 + lq * 4); \
      _Pragma("unroll")                                                  \
      for (int r = 0; r < 4; ++r) C[mt][r] = fmaf(hf[r], P[r], C[mt][r]); \
    }                                                                    \
  } while (0)

  LDW2(ba, b2a, rot);

  __syncthreads();  // HsT ready; last barrier — loop below is barrier-free

  f32x4 C[4] = {};
#pragma unroll 1
  for (int il = 0; il < 64; il += 2) {
    int i0 = (il + rot) & 63;
    int i1 = (il + 1 + rot) & 63;
    int i2 = (il + 2 + rot) & 63;
    LDW2(bb, b2b, i1);
    STEP(ba, b2a, i0);
    if (il < 62) LDW2(ba, b2a, i2);
    STEP(bb, b2b, i1);
  }
#undef LDW2
#undef STEP

  // scatter-add to neigh[dst]
#pragma unroll
  for (int mt = 0; mt < 4; ++mt) {
#pragma unroll
    for (int r = 0; r < 4; ++r) {
      int el = wave * 64 + mt * 16 + lq * 4 + r;
      if (e0 + el < NE)
        atomicAdd(neigh + (size_t)Ds[el] * D + ocol, C[mt][r]);
    }
  }
}

// ------- GRU: x=relu(neigh+cb); gates via split-bf16 MFMA; h in place; re-zeroes neigh -------
__global__ __launch_bounds__(256) void k_gru(float* __restrict__ neigh,
                                             float* __restrict__ h,
                                             const __hip_bfloat16* __restrict__ Bhi,
                                             const __hip_bfloat16* __restrict__ Blo,
                                             const float* __restrict__ cb,
                                             const float* __restrict__ bih,
                                             const float* __restrict__ bhh) {
  __shared__ __hip_bfloat16 Ahi[32 * 128];
  __shared__ __hip_bfloat16 Alo[32 * 128];
  int tid = threadIdx.x;
  int n0 = blockIdx.x * 32;  // NV % 32 == 0
  for (int idx = tid; idx < 32 * 64; idx += 256) {
    int node = idx >> 6, f = idx & 63;
    int gn = n0 + node;
    float xv = fmaxf(neigh[(size_t)gn * D + f] + cb[f], 0.f);
    neigh[(size_t)gn * D + f] = 0.f;  // ready for next step's atomics
    float hv = h[(size_t)gn * D + f];
    __hip_bfloat16 xh = __float2bfloat16(xv);
    __hip_bfloat16 hh = __float2bfloat16(hv);
    Ahi[node * 128 + f] = xh;
    Ahi[node * 128 + 64 + f] = hh;
    Alo[node * 128 + f] = __float2bfloat16(xv - __bfloat162float(xh));
    Alo[node * 128 + 64 + f] = __float2bfloat16(hv - __bfloat162float(hh));
  }
  __syncthreads();
  int wave = tid >> 6, lane = tid & 63;
  int lr = lane & 15, lq = lane >> 4;
  f32x4 acc[2][4] = {};  // [m-tile][gate-class]
#pragma unroll
  for (int ks = 0; ks < 4; ++ks) {
    int koff = ks * 32 + lq * 8;
    bf16x8 ah[2], al[2], bh[4], bl[4];
#pragma unroll
    for (int mt = 0; mt < 2; ++mt) {
      ah[mt] = *(const bf16x8*)(Ahi + (mt * 16 + lr) * 128 + koff);
      al[mt] = *(const bf16x8*)(Alo + (mt * 16 + lr) * 128 + koff);
    }
#pragma unroll
    for (int cls = 0; cls < 4; ++cls) {
      int n = cls * 64 + wave * 16 + lr;
      bh[cls] = *(const bf16x8*)(Bhi + (size_t)n * 128 + koff);
      bl[cls] = *(const bf16x8*)(Blo + (size_t)n * 128 + koff);
    }
#pragma unroll
    for (int mt = 0; mt < 2; ++mt)
#pragma unroll
      for (int cls = 0; cls < 4; ++cls) {
        acc[mt][cls] = __builtin_amdgcn_mfma_f32_16x16x32_bf16(ah[mt], bh[cls], acc[mt][cls], 0, 0, 0);
        acc[mt][cls] = __builtin_amdgcn_mfma_f32_16x16x32_bf16(al[mt], bh[cls], acc[mt][cls], 0, 0, 0);
        acc[mt][cls] = __builtin_amdgcn_mfma_f32_16x16x32_bf16(ah[mt], bl[cls], acc[mt][cls], 0, 0, 0);
      }
  }
  int o = wave * 16 + lr;
  float b_r = bih[o] + bhh[o];
  float b_z = bih[64 + o] + bhh[64 + o];
  float b_in = bih[128 + o];
  float b_hn = bhh[128 + o];
#pragma unroll
  for (int mt = 0; mt < 2; ++mt) {
#pragma unroll
    for (int r = 0; r < 4; ++r) {
      int gn = n0 + mt * 16 + lq * 4 + r;
      float rs = acc[mt][0][r] + b_r;
      float zs = acc[mt][1][r] + b_z;
      float inn = acc[mt][2][r] + b_in;
      float hnn = acc[mt][3][r] + b_hn;
      float rg = 1.f / (1.f + __expf(-rs));
      float zg = 1.f / (1.f + __expf(-zs));
      float a = inn + rg * hnn;
      a = fminf(fmaxf(a, -15.f), 15.f);
      float e2 = __expf(2.f * a);
      float nn = (e2 - 1.f) / (e2 + 1.f);
      float hold = h[(size_t)gn * D + o];
      h[(size_t)gn * D + o] = (1.f - zg) * nn + zg * hold;
    }
  }
}

// ---------------- predictor: score_e = [h_src | h_dst] . pW + pb ----------------
__global__ __launch_bounds__(256) void k_pred(const float* __restrict__ h,
                                              const int* __restrict__ src,
                                              const int* __restrict__ dst,
                                              const float* __restrict__ pW,
                                              const float* __restrict__ pb,
                                              float* __restrict__ out) {
  int wave = threadIdx.x >> 6, lane = threadIdx.x & 63;
  int e = blockIdx.x * 4 + wave;
  int s = src[e], d2 = dst[e];
  float v = h[(size_t)s * D + lane] * pW[lane] + h[(size_t)d2 * D + lane] * pW[64 + lane];
#pragma unroll
  for (int off = 32; off >= 1; off >>= 1) v += __shfl_xor(v, off, 64);
  if (lane == 0) out[e] = v + pb[0];
}

extern "C" void kernel_launch(void* const* d_in, const int* in_sizes, int n_in,
                              void* d_out, int out_size, void* d_ws, size_t ws_size,
                              hipStream_t stream) {
  const float* node_feats = (const float*)d_in[0];
  const float* edge_feats = (const float*)d_in[1];
  const int* src = (const int*)d_in[2];
  const int* dst = (const int*)d_in[3];
  const float* proj_W = (const float*)d_in[4];
  const float* proj_b = (const float*)d_in[5];
  const float* en_W1 = (const float*)d_in[6];
  const float* en_b1 = (const float*)d_in[7];
  const float* en_W2 = (const float*)d_in[8];
  const float* en_b2 = (const float*)d_in[9];
  const float* conv_b = (const float*)d_in[10];
  const float* gru_Wih = (const float*)d_in[11];
  const float* gru_Whh = (const float*)d_in[12];
  const float* gru_bih = (const float*)d_in[13];
  const float* gru_bhh = (const float*)d_in[14];
  const float* pred_W = (const float*)d_in[15];
  const float* pred_b = (const float*)d_in[16];

  char* ws = (char*)d_ws;
  size_t off = 0;
  auto walloc = [&](size_t bytes) -> void* {
    void* p = ws + off;
    off = (off + bytes + 255) & ~(size_t)255;
    return p;
  };
  // total workspace: ~22 MB
  float* h = (float*)walloc((size_t)NV * D * 4);
  float* neigh = (float*)walloc((size_t)NV * D * 4);
  __hip_bfloat16* t_bf = (__hip_bfloat16*)walloc((size_t)NE * EHID * 2);
  __hip_bfloat16* w2_bf = (__hip_bfloat16*)walloc((size_t)D * D * EHID * 2);
  __hip_bfloat16* Bhi = (__hip_bfloat16*)walloc((size_t)256 * 128 * 2);
  __hip_bfloat16* Blo = (__hip_bfloat16*)walloc((size_t)256 * 128 * 2);

  k_proj<<<NV / 4, 256, 0, stream>>>(node_feats, proj_W, proj_b, h, neigh);
  k_edge1<<<NE / 2, 256, 0, stream>>>(edge_feats, en_W1, en_b1, t_bf);
  k_cvt_w2<<<(D * D * EHID + 255) / 256, 256, 0, stream>>>(en_W2, w2_bf);
  k_build_b<<<128, 256, 0, stream>>>(gru_Wih, gru_Whh, Bhi, Blo);
  int msg_grid = ((NE + 255) / 256) * 4;
  for (int s = 0; s < NSTEPS; ++s) {
    k_msg<<<msg_grid, 256, 0, stream>>>(h, t_bf, w2_bf, en_b2, src, dst, neigh);
    k_gru<<<NV / 32, 256, 0, stream>>>(neigh, h, Bhi, Blo, conv_b, gru_bih, gru_bhh);
  }
  k_pred<<<NE / 4, 256, 0, stream>>>(h, src, dst, pred_W, pred_b, (float*)d_out);
}

// Round 8
// 888.925 us; speedup vs baseline: 1.0016x; 1.0016x over previous
//
#include <hip/hip_runtime.h>
#include <hip/hip_bf16.h>
#include <cstdint>

#define NV 20000
#define NE 40000
#define NODE_IN 74
#define EDGE_IN 12
#define D 64
#define EHID 128
#define NSTEPS 6

typedef __bf16 bf16x8 __attribute__((ext_vector_type(8)));
typedef float f32x4 __attribute__((ext_vector_type(4)));

// ---------------- node projection: h = relu(nf @ Wp^T + bp); also zero neigh ----------------
__global__ __launch_bounds__(256) void k_proj(const float* __restrict__ nf,
                                              const float* __restrict__ W,
                                              const float* __restrict__ b,
                                              float* __restrict__ h,
                                              float* __restrict__ neigh) {
  __shared__ float sn[4][NODE_IN];
  int tid = threadIdx.x;
  int nb = blockIdx.x * 4;
  for (int idx = tid; idx < 4 * NODE_IN; idx += 256) {
    int r = idx / NODE_IN, c = idx % NODE_IN;
    sn[r][c] = nf[(size_t)(nb + r) * NODE_IN + c];
  }
  __syncthreads();
  int nl = tid >> 6, o = tid & 63;
  float acc = b[o];
#pragma unroll
  for (int i = 0; i < NODE_IN; ++i) acc = fmaf(sn[nl][i], W[o * NODE_IN + i], acc);
  h[(size_t)(nb + nl) * D + o] = fmaxf(acc, 0.f);
  neigh[(size_t)(nb + nl) * D + o] = 0.f;
}

// ------------- edge net layer 1: t = relu(ef @ W1^T + b1), bf16 -------------
__global__ __launch_bounds__(256) void k_edge1(const float* __restrict__ ef,
                                               const float* __restrict__ W1,
                                               const float* __restrict__ b1,
                                               __hip_bfloat16* __restrict__ t_bf) {
  __shared__ float se[2][EDGE_IN];
  int tid = threadIdx.x;
  int eb = blockIdx.x * 2;
  if (tid < 2 * EDGE_IN)
    se[tid / EDGE_IN][tid % EDGE_IN] =
        ef[(size_t)(eb + tid / EDGE_IN) * EDGE_IN + tid % EDGE_IN];
  __syncthreads();
  int el = tid >> 7, k = tid & 127;
  float acc = b1[k];
#pragma unroll
  for (int j = 0; j < EDGE_IN; ++j) acc = fmaf(se[el][j], W1[k * EDGE_IN + j], acc);
  t_bf[(size_t)(eb + el) * EHID + k] = __float2bfloat16(fmaxf(acc, 0.f));
}

// ---------------- W2 fp32 -> bf16 ----------------
__global__ __launch_bounds__(256) void k_cvt_w2(const float* __restrict__ W2,
                                                __hip_bfloat16* __restrict__ w2b) {
  int idx = blockIdx.x * 256 + threadIdx.x;
  if (idx < D * D * EHID) w2b[idx] = __float2bfloat16(W2[idx]);
}

// ------- build GRU B matrix (256 x 128), hi/lo bf16 split -------
__global__ __launch_bounds__(256) void k_build_b(const float* __restrict__ Wih,
                                                 const float* __restrict__ Whh,
                                                 __hip_bfloat16* __restrict__ Bhi,
                                                 __hip_bfloat16* __restrict__ Blo) {
  int idx = blockIdx.x * 256 + threadIdx.x;  // 32768 total
  int n = idx >> 7, k = idx & 127;
  int o = n & 63, cls = n >> 6;
  float v;
  if (cls == 0)      v = (k < 64) ? Wih[o * 64 + k]         : Whh[o * 64 + (k - 64)];
  else if (cls == 1) v = (k < 64) ? Wih[(64 + o) * 64 + k]  : Whh[(64 + o) * 64 + (k - 64)];
  else if (cls == 2) v = (k < 64) ? Wih[(128 + o) * 64 + k] : 0.f;
  else               v = (k < 64) ? 0.f                     : Whh[(128 + o) * 64 + (k - 64)];
  __hip_bfloat16 hi = __float2bfloat16(v);
  Bhi[idx] = hi;
  Blo[idx] = __float2bfloat16(v - __bfloat162float(hi));
}

// ======== PATH A: materialized ew ========
// ew GEMM: ew(E x 4096 bf16) = t(E x 128) @ W2^T(4096 x 128) + b2.
// 128x128 tile, K=128 single stage, plain-load staging (NO global_load_lds —
// R1's crash is explained by its per-lane LDS address, the documented misuse).
__global__ __launch_bounds__(256) void k_ewgemm(const __hip_bfloat16* __restrict__ A,
                                                const __hip_bfloat16* __restrict__ B,
                                                const float* __restrict__ b2,
                                                __hip_bfloat16* __restrict__ ew) {
  __shared__ __align__(16) __hip_bfloat16 As[128 * 136];
  __shared__ __align__(16) __hip_bfloat16 Bs[128 * 136];
  int tid = threadIdx.x;
  int e0 = blockIdx.x * 128, n0 = blockIdx.y * 128;
#pragma unroll
  for (int it = 0; it < 8; ++it) {
    int chunk = it * 256 + tid;
    int row = chunk >> 4, c16 = chunk & 15;
    int ge = e0 + row; if (ge > NE - 1) ge = NE - 1;
    *(uint4*)(As + row * 136 + c16 * 8) = *(const uint4*)(A + (size_t)ge * EHID + c16 * 8);
    *(uint4*)(Bs + row * 136 + c16 * 8) = *(const uint4*)(B + (size_t)(n0 + row) * EHID + c16 * 8);
  }
  __syncthreads();
  int wave = tid >> 6, lane = tid & 63;
  int wm = wave & 1, wn = wave >> 1;
  int lr = lane & 15, lq = lane >> 4;
  f32x4 acc[4][4] = {};
#pragma unroll
  for (int ks = 0; ks < 4; ++ks) {
    bf16x8 af[4], bfr[4];
#pragma unroll
    for (int mt = 0; mt < 4; ++mt)
      af[mt] = *(const bf16x8*)(As + (wm * 64 + mt * 16 + lr) * 136 + ks * 32 + lq * 8);
#pragma unroll
    for (int nt = 0; nt < 4; ++nt)
      bfr[nt] = *(const bf16x8*)(Bs + (wn * 64 + nt * 16 + lr) * 136 + ks * 32 + lq * 8);
#pragma unroll
    for (int mt = 0; mt < 4; ++mt)
#pragma unroll
      for (int nt = 0; nt < 4; ++nt)
        acc[mt][nt] = __builtin_amdgcn_mfma_f32_16x16x32_bf16(af[mt], bfr[nt], acc[mt][nt], 0, 0, 0);
  }
#pragma unroll
  for (int nt = 0; nt < 4; ++nt) {
    int gn = n0 + wn * 64 + nt * 16 + lr;
    float b2v = b2[gn];
#pragma unroll
    for (int mt = 0; mt < 4; ++mt) {
#pragma unroll
      for (int r = 0; r < 4; ++r) {
        int gm = e0 + wm * 64 + mt * 16 + lq * 4 + r;
        if (gm < NE) ew[(size_t)gm * 4096 + gn] = __float2bfloat16(acc[mt][nt][r] + b2v);
      }
    }
  }
}

// message pass from materialized ew: pure HBM stream. 2 edges/wave, 4 waves/block.
// Per edge: wave reads the 8 KB ew row in 8 coalesced 1 KB chunks; lane's 8 elems
// share one i = c*8 + (lane>>3), cover o = (lane&7)*8..+8; shuffle-reduce; atomics.
#define ACC8(A, V, HH) do {                                        \
    A[0] = fmaf(HH, __uint_as_float(V.x << 16), A[0]);             \
    A[1] = fmaf(HH, __uint_as_float(V.x & 0xffff0000u), A[1]);     \
    A[2] = fmaf(HH, __uint_as_float(V.y << 16), A[2]);             \
    A[3] = fmaf(HH, __uint_as_float(V.y & 0xffff0000u), A[3]);     \
    A[4] = fmaf(HH, __uint_as_float(V.z << 16), A[4]);             \
    A[5] = fmaf(HH, __uint_as_float(V.z & 0xffff0000u), A[5]);     \
    A[6] = fmaf(HH, __uint_as_float(V.w << 16), A[6]);             \
    A[7] = fmaf(HH, __uint_as_float(V.w & 0xffff0000u), A[7]);     \
  } while (0)
__global__ __launch_bounds__(256) void k_msg_ew(const float* __restrict__ h,
                                                const __hip_bfloat16* __restrict__ ew,
                                                const int* __restrict__ src,
                                                const int* __restrict__ dst,
                                                float* __restrict__ neigh) {
  int wave = threadIdx.x >> 6, lane = threadIdx.x & 63;
  int e = (blockIdx.x * 4 + wave) * 2;   // NE % 8 == 0
  int s0 = src[e],     d0 = dst[e];
  int s1 = src[e + 1], d1 = dst[e + 1];
  float hv0 = h[(size_t)s0 * D + lane];
  float hv1 = h[(size_t)s1 * D + lane];
  float a0[8] = {}, a1[8] = {};
  const uint4* p0 = (const uint4*)(ew + (size_t)e * 4096);
  const uint4* p1 = (const uint4*)(ew + (size_t)(e + 1) * 4096);
#pragma unroll
  for (int c = 0; c < 8; ++c) {
    uint4 v0 = p0[c * 64 + lane];
    uint4 v1 = p1[c * 64 + lane];
    float h0 = __shfl(hv0, c * 8 + (lane >> 3), 64);
    float h1 = __shfl(hv1, c * 8 + (lane >> 3), 64);
    ACC8(a0, v0, h0);
    ACC8(a1, v1, h1);
  }
#pragma unroll
  for (int j = 0; j < 8; ++j) {
    a0[j] += __shfl_xor(a0[j], 8, 64);
    a0[j] += __shfl_xor(a0[j], 16, 64);
    a0[j] += __shfl_xor(a0[j], 32, 64);
    a1[j] += __shfl_xor(a1[j], 8, 64);
    a1[j] += __shfl_xor(a1[j], 16, 64);
    a1[j] += __shfl_xor(a1[j], 32, 64);
  }
  if (lane < 8) {
    float* np = neigh + (size_t)d0 * D + lane * 8;
#pragma unroll
    for (int j = 0; j < 8; ++j) atomicAdd(np + j, a0[j]);
  }
  if (lane >= 32 && lane < 40) {
    float* np = neigh + (size_t)d1 * D + (lane - 32) * 8;
#pragma unroll
    for (int j = 0; j < 8; ++j) atomicAdd(np + j, a1[j]);
  }
}

// ======== PATH B fallback: R7 fused k_msg (verbatim) ========
#define HS_STRIDE 260
__global__ __launch_bounds__(256) void k_msg(const float* __restrict__ h,
                                             const __hip_bfloat16* __restrict__ t_bf,
                                             const __hip_bfloat16* __restrict__ w2,
                                             const float* __restrict__ b2,
                                             const int* __restrict__ src,
                                             const int* __restrict__ dst,
                                             float* __restrict__ neigh) {
  __shared__ __align__(16) float HsT[64 * HS_STRIDE];
  __shared__ int Ss[256];
  __shared__ int Ds[256];
  int tid = threadIdx.x;
  int eblk = blockIdx.x >> 2, cg = blockIdx.x & 3;
  int e0 = eblk * 256;
  int rot = (blockIdx.x * 17) & 63;
  {
    int e = e0 + tid; if (e > NE - 1) e = NE - 1;
    Ss[tid] = src[e];
    Ds[tid] = dst[e];
  }
  __syncthreads();
  for (int idx = tid; idx < 256 * 64; idx += 256) {
    int r = idx >> 6, i = idx & 63;
    HsT[i * HS_STRIDE + r] = h[(size_t)Ss[r] * D + i];
  }
  int wave = tid >> 6, lane = tid & 63;
  int lr = lane & 15, lq = lane >> 4;
  const int ocol = cg * 16 + lr;
  bf16x8 tf[4][4];
#pragma unroll
  for (int mt = 0; mt < 4; ++mt) {
    int er = e0 + wave * 64 + mt * 16 + lr; if (er > NE - 1) er = NE - 1;
#pragma unroll
    for (int ks = 0; ks < 4; ++ks)
      tf[mt][ks] = *(const bf16x8*)(t_bf + (size_t)er * EHID + ks * 32 + lq * 8);
  }
  const __hip_bfloat16* wbase = w2 + (size_t)ocol * EHID + lq * 8;
  bf16x8 ba0, ba1, ba2, ba3, bb0, bb1, bb2, bb3;
  float b2a, b2b;
#define LDW2(BUF, B2V, IG) do {                                          \
    const __hip_bfloat16* wp_ = wbase + (size_t)(IG) * (64 * EHID);      \
    BUF##0 = *(const bf16x8*)(wp_);                                      \
    BUF##1 = *(const bf16x8*)(wp_ + 32);                                 \
    BUF##2 = *(const bf16x8*)(wp_ + 64);                                 \
    BUF##3 = *(const bf16x8*)(wp_ + 96);                                 \
    B2V = b2[(IG) * 64 + ocol];                                          \
  } while (0)
#define STEP(BUF, B2V, IG) do {                                          \
    _Pragma("unroll")                                                    \
    for (int mt = 0; mt < 4; ++mt) {                                     \
      f32x4 P = {B2V, B2V, B2V, B2V};                                    \
      P = __builtin_amdgcn_mfma_f32_16x16x32_bf16(tf[mt][0], BUF##0, P, 0, 0, 0); \
      P = __builtin_amdgcn_mfma_f32_16x16x32_bf16(tf[mt][1], BUF##1, P, 0, 0, 0); \
      P = __builtin_amdgcn_mfma_f32_16x16x32_bf16(tf[mt][2], BUF##2, P, 0, 0, 0); \
      P = __builtin_amdgcn_mfma_f32_16x16x32_bf16(tf[mt][3], BUF##3, P, 0, 0, 0); \
      f32x4 hf = *(const f32x4*)(HsT + (IG) * HS_STRIDE + wave * 64 + mt * 16 + lq * 4); \
      _Pragma("unroll")                                                  \
      for (int r = 0; r < 4; ++r) C[mt][r] = fmaf(hf[r], P[r], C[mt][r]); \
    }                                                                    \
  } while (0)
  LDW2(ba, b2a, rot);
  __syncthreads();
  f32x4 C[4] = {};
#pragma unroll 1
  for (int il = 0; il < 64; il += 2) {
    int i0 = (il + rot) & 63;
    int i1 = (il + 1 + rot) & 63;
    int i2 = (il + 2 + rot) & 63;
    LDW2(bb, b2b, i1);
    STEP(ba, b2a, i0);
    if (il < 62) LDW2(ba, b2a, i2);
    STEP(bb, b2b, i1);
  }
#undef LDW2
#undef STEP
#pragma unroll
  for (int mt = 0; mt < 4; ++mt) {
#pragma unroll
    for (int r = 0; r < 4; ++r) {
      int el = wave * 64 + mt * 16 + lq * 4 + r;
      if (e0 + el < NE)
        atomicAdd(neigh + (size_t)Ds[el] * D + ocol, C[mt][r]);
    }
  }
}

// ------- GRU: x=relu(neigh+cb); gates via split-bf16 MFMA; h in place; re-zeroes neigh -------
__global__ __launch_bounds__(256) void k_gru(float* __restrict__ neigh,
                                             float* __restrict__ h,
                                             const __hip_bfloat16* __restrict__ Bhi,
                                             const __hip_bfloat16* __restrict__ Blo,
                                             const float* __restrict__ cb,
                                             const float* __restrict__ bih,
                                             const float* __restrict__ bhh) {
  __shared__ __hip_bfloat16 Ahi[32 * 128];
  __shared__ __hip_bfloat16 Alo[32 * 128];
  int tid = threadIdx.x;
  int n0 = blockIdx.x * 32;  // NV % 32 == 0
  for (int idx = tid; idx < 32 * 64; idx += 256) {
    int node = idx >> 6, f = idx & 63;
    int gn = n0 + node;
    float xv = fmaxf(neigh[(size_t)gn * D + f] + cb[f], 0.f);
    neigh[(size_t)gn * D + f] = 0.f;
    float hv = h[(size_t)gn * D + f];
    __hip_bfloat16 xh = __float2bfloat16(xv);
    __hip_bfloat16 hh = __float2bfloat16(hv);
    Ahi[node * 128 + f] = xh;
    Ahi[node * 128 + 64 + f] = hh;
    Alo[node * 128 + f] = __float2bfloat16(xv - __bfloat162float(xh));
    Alo[node * 128 + 64 + f] = __float2bfloat16(hv - __bfloat162float(hh));
  }
  __syncthreads();
  int wave = tid >> 6, lane = tid & 63;
  int lr = lane & 15, lq = lane >> 4;
  f32x4 acc[2][4] = {};
#pragma unroll
  for (int ks = 0; ks < 4; ++ks) {
    int koff = ks * 32 + lq * 8;
    bf16x8 ah[2], al[2], bh[4], bl[4];
#pragma unroll
    for (int mt = 0; mt < 2; ++mt) {
      ah[mt] = *(const bf16x8*)(Ahi + (mt * 16 + lr) * 128 + koff);
      al[mt] = *(const bf16x8*)(Alo + (mt * 16 + lr) * 128 + koff);
    }
#pragma unroll
    for (int cls = 0; cls < 4; ++cls) {
      int n = cls * 64 + wave * 16 + lr;
      bh[cls] = *(const bf16x8*)(Bhi + (size_t)n * 128 + koff);
      bl[cls] = *(const bf16x8*)(Blo + (size_t)n * 128 + koff);
    }
#pragma unroll
    for (int mt = 0; mt < 2; ++mt)
#pragma unroll
      for (int cls = 0; cls < 4; ++cls) {
        acc[mt][cls] = __builtin_amdgcn_mfma_f32_16x16x32_bf16(ah[mt], bh[cls], acc[mt][cls], 0, 0, 0);
        acc[mt][cls] = __builtin_amdgcn_mfma_f32_16x16x32_bf16(al[mt], bh[cls], acc[mt][cls], 0, 0, 0);
        acc[mt][cls] = __builtin_amdgcn_mfma_f32_16x16x32_bf16(ah[mt], bl[cls], acc[mt][cls], 0, 0, 0);
      }
  }
  int o = wave * 16 + lr;
  float b_r = bih[o] + bhh[o];
  float b_z = bih[64 + o] + bhh[64 + o];
  float b_in = bih[128 + o];
  float b_hn = bhh[128 + o];
#pragma unroll
  for (int mt = 0; mt < 2; ++mt) {
#pragma unroll
    for (int r = 0; r < 4; ++r) {
      int gn = n0 + mt * 16 + lq * 4 + r;
      float rs = acc[mt][0][r] + b_r;
      float zs = acc[mt][1][r] + b_z;
      float inn = acc[mt][2][r] + b_in;
      float hnn = acc[mt][3][r] + b_hn;
      float rg = 1.f / (1.f + __expf(-rs));
      float zg = 1.f / (1.f + __expf(-zs));
      float a = inn + rg * hnn;
      a = fminf(fmaxf(a, -15.f), 15.f);
      float e2 = __expf(2.f * a);
      float nn = (e2 - 1.f) / (e2 + 1.f);
      float hold = h[(size_t)gn * D + o];
      h[(size_t)gn * D + o] = (1.f - zg) * nn + zg * hold;
    }
  }
}

// ---------------- predictor: score_e = [h_src | h_dst] . pW + pb ----------------
__global__ __launch_bounds__(256) void k_pred(const float* __restrict__ h,
                                              const int* __restrict__ src,
                                              const int* __restrict__ dst,
                                              const float* __restrict__ pW,
                                              const float* __restrict__ pb,
                                              float* __restrict__ out) {
  int wave = threadIdx.x >> 6, lane = threadIdx.x & 63;
  int e = blockIdx.x * 4 + wave;
  int s = src[e], d2 = dst[e];
  float v = h[(size_t)s * D + lane] * pW[lane] + h[(size_t)d2 * D + lane] * pW[64 + lane];
#pragma unroll
  for (int off = 32; off >= 1; off >>= 1) v += __shfl_xor(v, off, 64);
  if (lane == 0) out[e] = v + pb[0];
}

extern "C" void kernel_launch(void* const* d_in, const int* in_sizes, int n_in,
                              void* d_out, int out_size, void* d_ws, size_t ws_size,
                              hipStream_t stream) {
  const float* node_feats = (const float*)d_in[0];
  const float* edge_feats = (const float*)d_in[1];
  const int* src = (const int*)d_in[2];
  const int* dst = (const int*)d_in[3];
  const float* proj_W = (const float*)d_in[4];
  const float* proj_b = (const float*)d_in[5];
  const float* en_W1 = (const float*)d_in[6];
  const float* en_b1 = (const float*)d_in[7];
  const float* en_W2 = (const float*)d_in[8];
  const float* en_b2 = (const float*)d_in[9];
  const float* conv_b = (const float*)d_in[10];
  const float* gru_Wih = (const float*)d_in[11];
  const float* gru_Whh = (const float*)d_in[12];
  const float* gru_bih = (const float*)d_in[13];
  const float* gru_bhh = (const float*)d_in[14];
  const float* pred_W = (const float*)d_in[15];
  const float* pred_b = (const float*)d_in[16];

  char* ws = (char*)d_ws;
  size_t off = 0;
  auto walloc = [&](size_t bytes) -> void* {
    void* p = ws + off;
    off = (off + bytes + 255) & ~(size_t)255;
    return p;
  };
  float* h = (float*)walloc((size_t)NV * D * 4);
  float* neigh = (float*)walloc((size_t)NV * D * 4);
  __hip_bfloat16* t_bf = (__hip_bfloat16*)walloc((size_t)NE * EHID * 2);
  __hip_bfloat16* w2_bf = (__hip_bfloat16*)walloc((size_t)D * D * EHID * 2);
  __hip_bfloat16* Bhi = (__hip_bfloat16*)walloc((size_t)256 * 128 * 2);
  __hip_bfloat16* Blo = (__hip_bfloat16*)walloc((size_t)256 * 128 * 2);
  size_t ew_bytes = (size_t)NE * 4096 * 2;  // 327.68 MB
  bool big = (off + ew_bytes + 256) <= ws_size;

  k_proj<<<NV / 4, 256, 0, stream>>>(node_feats, proj_W, proj_b, h, neigh);
  k_edge1<<<NE / 2, 256, 0, stream>>>(edge_feats, en_W1, en_b1, t_bf);
  k_cvt_w2<<<(D * D * EHID + 255) / 256, 256, 0, stream>>>(en_W2, w2_bf);
  k_build_b<<<128, 256, 0, stream>>>(gru_Wih, gru_Whh, Bhi, Blo);

  if (big) {
    __hip_bfloat16* ewb = (__hip_bfloat16*)walloc(ew_bytes);
    k_ewgemm<<<dim3((NE + 127) / 128, 32), 256, 0, stream>>>(t_bf, w2_bf, en_b2, ewb);
    for (int s = 0; s < NSTEPS; ++s) {
      k_msg_ew<<<NE / 8, 256, 0, stream>>>(h, ewb, src, dst, neigh);
      k_gru<<<NV / 32, 256, 0, stream>>>(neigh, h, Bhi, Blo, conv_b, gru_bih, gru_bhh);
    }
  } else {
    int msg_grid = ((NE + 255) / 256) * 4;
    for (int s = 0; s < NSTEPS; ++s) {
      k_msg<<<msg_grid, 256, 0, stream>>>(h, t_bf, w2_bf, en_b2, src, dst, neigh);
      k_gru<<<NV / 32, 256, 0, stream>>>(neigh, h, Bhi, Blo, conv_b, gru_bih, gru_bhh);
    }
  }
  k_pred<<<NE / 4, 256, 0, stream>>>(h, src, dst, pred_W, pred_b, (float*)d_out);
}

// Round 9
// 593.616 us; speedup vs baseline: 1.4999x; 1.4975x over previous
//
#include <hip/hip_runtime.h>
#include <hip/hip_bf16.h>
#include <cstdint>

#define NV 20000
#define NE 40000
#define NODE_IN 74
#define EDGE_IN 12
#define D 64
#define EHID 128
#define NSTEPS 6

typedef __bf16 bf16x8 __attribute__((ext_vector_type(8)));
typedef float f32x4 __attribute__((ext_vector_type(4)));

// ---------------- node projection: h = relu(nf @ Wp^T + bp); also zero neigh ----------------
__global__ __launch_bounds__(256) void k_proj(const float* __restrict__ nf,
                                              const float* __restrict__ W,
                                              const float* __restrict__ b,
                                              float* __restrict__ h,
                                              float* __restrict__ neigh) {
  __shared__ float sn[4][NODE_IN];
  int tid = threadIdx.x;
  int nb = blockIdx.x * 4;
  for (int idx = tid; idx < 4 * NODE_IN; idx += 256) {
    int r = idx / NODE_IN, c = idx % NODE_IN;
    sn[r][c] = nf[(size_t)(nb + r) * NODE_IN + c];
  }
  __syncthreads();
  int nl = tid >> 6, o = tid & 63;
  float acc = b[o];
#pragma unroll
  for (int i = 0; i < NODE_IN; ++i) acc = fmaf(sn[nl][i], W[o * NODE_IN + i], acc);
  h[(size_t)(nb + nl) * D + o] = fmaxf(acc, 0.f);
  neigh[(size_t)(nb + nl) * D + o] = 0.f;
}

// ------------- edge net layer 1: t = relu(ef @ W1^T + b1), bf16 -------------
__global__ __launch_bounds__(256) void k_edge1(const float* __restrict__ ef,
                                               const float* __restrict__ W1,
                                               const float* __restrict__ b1,
                                               __hip_bfloat16* __restrict__ t_bf) {
  __shared__ float se[2][EDGE_IN];
  int tid = threadIdx.x;
  int eb = blockIdx.x * 2;
  if (tid < 2 * EDGE_IN)
    se[tid / EDGE_IN][tid % EDGE_IN] =
        ef[(size_t)(eb + tid / EDGE_IN) * EDGE_IN + tid % EDGE_IN];
  __syncthreads();
  int el = tid >> 7, k = tid & 127;
  float acc = b1[k];
#pragma unroll
  for (int j = 0; j < EDGE_IN; ++j) acc = fmaf(se[el][j], W1[k * EDGE_IN + j], acc);
  t_bf[(size_t)(eb + el) * EHID + k] = __float2bfloat16(fmaxf(acc, 0.f));
}

// ---------------- W2 fp32 -> bf16 ----------------
__global__ __launch_bounds__(256) void k_cvt_w2(const float* __restrict__ W2,
                                                __hip_bfloat16* __restrict__ w2b) {
  int idx = blockIdx.x * 256 + threadIdx.x;
  if (idx < D * D * EHID) w2b[idx] = __float2bfloat16(W2[idx]);
}

// ---------------- b2 transpose: b2t[o][i] = b2[i*64+o], bf16 ----------------
__global__ __launch_bounds__(256) void k_b2t(const float* __restrict__ b2,
                                             __hip_bfloat16* __restrict__ b2t) {
  int idx = blockIdx.x * 256 + threadIdx.x;  // 4096
  int o = idx >> 6, i = idx & 63;
  b2t[o * 64 + i] = __float2bfloat16(b2[i * 64 + o]);
}

// ------- build GRU B matrix (256 x 128), hi/lo bf16 split -------
__global__ __launch_bounds__(256) void k_build_b(const float* __restrict__ Wih,
                                                 const float* __restrict__ Whh,
                                                 __hip_bfloat16* __restrict__ Bhi,
                                                 __hip_bfloat16* __restrict__ Blo) {
  int idx = blockIdx.x * 256 + threadIdx.x;  // 32768 total
  int n = idx >> 7, k = idx & 127;
  int o = n & 63, cls = n >> 6;
  float v;
  if (cls == 0)      v = (k < 64) ? Wih[o * 64 + k]         : Whh[o * 64 + (k - 64)];
  else if (cls == 1) v = (k < 64) ? Wih[(64 + o) * 64 + k]  : Whh[(64 + o) * 64 + (k - 64)];
  else if (cls == 2) v = (k < 64) ? Wih[(128 + o) * 64 + k] : 0.f;
  else               v = (k < 64) ? 0.f                     : Whh[(128 + o) * 64 + (k - 64)];
  __hip_bfloat16 hi = __float2bfloat16(v);
  Bhi[idx] = hi;
  Blo[idx] = __float2bfloat16(v - __bfloat162float(hi));
}

// ------- fused NNConv message+aggregate: W2-slice persistent in LDS -------
// Grid: 256 blocks = cg(4 colgroups of 16) x ih(2 i-halves of 32) x s(32 stripes
// of 1280 edges). 512 threads = 4 teams x 2 waves; team processes 64-edge tiles
// (5 rounds), wave = 2 m-tiles. Block loads its W2 slice (32i x 16o x 128k bf16 =
// 128 KB, XOR-swizzled) into LDS ONCE; inner i-loop = ds_read + MFMA only: no
// global loads, no barriers. b2-term = 1 extra MFMA vs pre-transposed b2t.
__global__ __launch_bounds__(512, 2) void k_msg(const float* __restrict__ h,
                                                const __hip_bfloat16* __restrict__ t_bf,
                                                const __hip_bfloat16* __restrict__ w2,
                                                const __hip_bfloat16* __restrict__ b2t,
                                                const int* __restrict__ src,
                                                const int* __restrict__ dst,
                                                float* __restrict__ neigh) {
  __shared__ __hip_bfloat16 W2s[512 * 128];      // 128 KB, row = ig*16+ol, swizzled k-chunks
  __shared__ __hip_bfloat16 Hs[4][32 * 64];      // 16 KB, [team][ig][e_local] bf16
  int tid = threadIdx.x;
  int bx = blockIdx.x;
  int cg = bx >> 6, ih = (bx >> 5) & 1, s = bx & 31;
  int lane = tid & 63, lr = lane & 15, lq = lane >> 4;
  int wave = tid >> 6;
  int team = wave >> 1, mthalf = wave & 1;
  int lane128 = tid & 127;
  const int ocol = cg * 16 + lr;

  // ---- load W2 slice into LDS (once) ----
#pragma unroll
  for (int it = 0; it < 16; ++it) {
    int chunk = it * 512 + tid;          // 8192 chunks of 8 elems
    int row = chunk >> 4, c = chunk & 15;
    int ig = row >> 4, ol = row & 15;
    const __hip_bfloat16* gp =
        w2 + ((size_t)((ih * 32 + ig) * 64 + cg * 16 + ol)) * EHID + c * 8;
    *(bf16x8*)(W2s + row * 128 + ((c ^ ol) * 8)) = *(const bf16x8*)gp;
  }
  // loop-invariant b2 B-frag
  bf16x8 b2frag = *(const bf16x8*)(b2t + (size_t)ocol * 64 + ih * 32 + lq * 8);

  int nt = (s < 31) ? 20 : 5;  // full 64-edge tiles in this stripe (40000 = 31*1280+320)

#pragma unroll 1
  for (int r5 = 0; r5 < 5; ++r5) {
    int t = r5 * 4 + team;
    int e0t = s * 1280 + t * 64;
    bool valid = (t < nt);
    __syncthreads();  // previous round's readers done before overwriting Hs
    if (valid) {
      // gather h[src] for this tile -> Hs[team][ig][e], bf16
      int e_l = lane128 & 63, hh = lane128 >> 6;
      int s_e = src[e0t + e_l];
      const float* hrow = h + (size_t)s_e * D + ih * 32 + hh * 16;
#pragma unroll
      for (int j4 = 0; j4 < 4; ++j4) {
        float4 hv = *(const float4*)(hrow + j4 * 4);
        int i0 = hh * 16 + j4 * 4;
        Hs[team][(i0 + 0) * 64 + e_l] = __float2bfloat16(hv.x);
        Hs[team][(i0 + 1) * 64 + e_l] = __float2bfloat16(hv.y);
        Hs[team][(i0 + 2) * 64 + e_l] = __float2bfloat16(hv.z);
        Hs[team][(i0 + 3) * 64 + e_l] = __float2bfloat16(hv.w);
      }
    }
    __syncthreads();  // Hs ready
    if (!valid) continue;

    const __hip_bfloat16* Ht = Hs[team];
    int mt2 = mthalf * 2;
    // t-frags for this wave's 2 m-tiles
    bf16x8 tf[2][4];
#pragma unroll
    for (int mt = 0; mt < 2; ++mt)
#pragma unroll
      for (int ks = 0; ks < 4; ++ks)
        tf[mt][ks] = *(const bf16x8*)(t_bf + (size_t)(e0t + (mt2 + mt) * 16 + lr) * EHID +
                                      ks * 32 + lq * 8);
    // C init = b2-term via one MFMA per m-tile: A = h (e x 32i), B = b2t slice
    f32x4 C0, C1;
    {
      bf16x8 af0, af1;
#pragma unroll
      for (int j = 0; j < 8; ++j) {
        af0[j] = *(const __bf16*)(Ht + (lq * 8 + j) * 64 + mt2 * 16 + lr);
        af1[j] = *(const __bf16*)(Ht + (lq * 8 + j) * 64 + (mt2 + 1) * 16 + lr);
      }
      f32x4 z = {0.f, 0.f, 0.f, 0.f};
      C0 = __builtin_amdgcn_mfma_f32_16x16x32_bf16(af0, b2frag, z, 0, 0, 0);
      C1 = __builtin_amdgcn_mfma_f32_16x16x32_bf16(af1, b2frag, z, 0, 0, 0);
    }
    // swizzled per-lane k-chunk offsets
    int sw0 = (((0 * 4 + lq) ^ lr) * 8);
    int sw1 = (((1 * 4 + lq) ^ lr) * 8);
    int sw2 = (((2 * 4 + lq) ^ lr) * 8);
    int sw3 = (((3 * 4 + lq) ^ lr) * 8);
    int e0q0 = mt2 * 16 + lq * 4;        // h-scale addr for mt 0
    int e0q1 = (mt2 + 1) * 16 + lq * 4;  // and mt 1

#pragma unroll 2
    for (int ig = 0; ig < 32; ++ig) {
      const __hip_bfloat16* Wr = W2s + (ig * 16 + lr) * 128;
      bf16x8 f0 = *(const bf16x8*)(Wr + sw0);
      bf16x8 f1 = *(const bf16x8*)(Wr + sw1);
      bf16x8 f2 = *(const bf16x8*)(Wr + sw2);
      bf16x8 f3 = *(const bf16x8*)(Wr + sw3);
      uint2 hA = *(const uint2*)(Ht + ig * 64 + e0q0);
      uint2 hB = *(const uint2*)(Ht + ig * 64 + e0q1);
      f32x4 P0 = {0.f, 0.f, 0.f, 0.f};
      P0 = __builtin_amdgcn_mfma_f32_16x16x32_bf16(tf[0][0], f0, P0, 0, 0, 0);
      P0 = __builtin_amdgcn_mfma_f32_16x16x32_bf16(tf[0][1], f1, P0, 0, 0, 0);
      P0 = __builtin_amdgcn_mfma_f32_16x16x32_bf16(tf[0][2], f2, P0, 0, 0, 0);
      P0 = __builtin_amdgcn_mfma_f32_16x16x32_bf16(tf[0][3], f3, P0, 0, 0, 0);
      f32x4 P1 = {0.f, 0.f, 0.f, 0.f};
      P1 = __builtin_amdgcn_mfma_f32_16x16x32_bf16(tf[1][0], f0, P1, 0, 0, 0);
      P1 = __builtin_amdgcn_mfma_f32_16x16x32_bf16(tf[1][1], f1, P1, 0, 0, 0);
      P1 = __builtin_amdgcn_mfma_f32_16x16x32_bf16(tf[1][2], f2, P1, 0, 0, 0);
      P1 = __builtin_amdgcn_mfma_f32_16x16x32_bf16(tf[1][3], f3, P1, 0, 0, 0);
      C0[0] = fmaf(__uint_as_float(hA.x << 16), P0[0], C0[0]);
      C0[1] = fmaf(__uint_as_float(hA.x & 0xffff0000u), P0[1], C0[1]);
      C0[2] = fmaf(__uint_as_float(hA.y << 16), P0[2], C0[2]);
      C0[3] = fmaf(__uint_as_float(hA.y & 0xffff0000u), P0[3], C0[3]);
      C1[0] = fmaf(__uint_as_float(hB.x << 16), P1[0], C1[0]);
      C1[1] = fmaf(__uint_as_float(hB.x & 0xffff0000u), P1[1], C1[1]);
      C1[2] = fmaf(__uint_as_float(hB.y << 16), P1[2], C1[2]);
      C1[3] = fmaf(__uint_as_float(hB.y & 0xffff0000u), P1[3], C1[3]);
    }
    // scatter-add partials (i-halves merge via atomics)
#pragma unroll
    for (int r = 0; r < 4; ++r) {
      int ea = e0t + e0q0 + r;
      atomicAdd(neigh + (size_t)dst[ea] * D + ocol, C0[r]);
      int eb = e0t + e0q1 + r;
      atomicAdd(neigh + (size_t)dst[eb] * D + ocol, C1[r]);
    }
  }
}

// ------- GRU: 64 nodes/block; x=relu(neigh+cb); split-bf16 MFMA; re-zeroes neigh -------
__global__ __launch_bounds__(256) void k_gru(float* __restrict__ neigh,
                                             float* __restrict__ h,
                                             const __hip_bfloat16* __restrict__ Bhi,
                                             const __hip_bfloat16* __restrict__ Blo,
                                             const float* __restrict__ cb,
                                             const float* __restrict__ bih,
                                             const float* __restrict__ bhh) {
  __shared__ __hip_bfloat16 Ahi[64 * 128];
  __shared__ __hip_bfloat16 Alo[64 * 128];
  int tid = threadIdx.x;
  int n0 = blockIdx.x * 64;
  for (int idx = tid; idx < 64 * 64; idx += 256) {
    int node = idx >> 6, f = idx & 63;
    int gn = n0 + node;
    int gc = gn < NV ? gn : NV - 1;
    float xv = fmaxf(neigh[(size_t)gc * D + f] + cb[f], 0.f);
    if (gn < NV) neigh[(size_t)gn * D + f] = 0.f;
    float hv = h[(size_t)gc * D + f];
    __hip_bfloat16 xh = __float2bfloat16(xv);
    __hip_bfloat16 hh = __float2bfloat16(hv);
    Ahi[node * 128 + f] = xh;
    Ahi[node * 128 + 64 + f] = hh;
    Alo[node * 128 + f] = __float2bfloat16(xv - __bfloat162float(xh));
    Alo[node * 128 + 64 + f] = __float2bfloat16(hv - __bfloat162float(hh));
  }
  __syncthreads();
  int wave = tid >> 6, lane = tid & 63;
  int lr = lane & 15, lq = lane >> 4;
  f32x4 acc[4][4] = {};  // [m-tile][gate-class]
#pragma unroll
  for (int ks = 0; ks < 4; ++ks) {
    int koff = ks * 32 + lq * 8;
    bf16x8 ah[4], al[4], bh[4], bl[4];
#pragma unroll
    for (int mt = 0; mt < 4; ++mt) {
      ah[mt] = *(const bf16x8*)(Ahi + (mt * 16 + lr) * 128 + koff);
      al[mt] = *(const bf16x8*)(Alo + (mt * 16 + lr) * 128 + koff);
    }
#pragma unroll
    for (int cls = 0; cls < 4; ++cls) {
      int n = cls * 64 + wave * 16 + lr;
      bh[cls] = *(const bf16x8*)(Bhi + (size_t)n * 128 + koff);
      bl[cls] = *(const bf16x8*)(Blo + (size_t)n * 128 + koff);
    }
#pragma unroll
    for (int mt = 0; mt < 4; ++mt)
#pragma unroll
      for (int cls = 0; cls < 4; ++cls) {
        acc[mt][cls] = __builtin_amdgcn_mfma_f32_16x16x32_bf16(ah[mt], bh[cls], acc[mt][cls], 0, 0, 0);
        acc[mt][cls] = __builtin_amdgcn_mfma_f32_16x16x32_bf16(al[mt], bh[cls], acc[mt][cls], 0, 0, 0);
        acc[mt][cls] = __builtin_amdgcn_mfma_f32_16x16x32_bf16(ah[mt], bl[cls], acc[mt][cls], 0, 0, 0);
      }
  }
  int o = wave * 16 + lr;
  float b_r = bih[o] + bhh[o];
  float b_z = bih[64 + o] + bhh[64 + o];
  float b_in = bih[128 + o];
  float b_hn = bhh[128 + o];
#pragma unroll
  for (int mt = 0; mt < 4; ++mt) {
#pragma unroll
    for (int r = 0; r < 4; ++r) {
      int gn = n0 + mt * 16 + lq * 4 + r;
      if (gn < NV) {
        float rs = acc[mt][0][r] + b_r;
        float zs = acc[mt][1][r] + b_z;
        float inn = acc[mt][2][r] + b_in;
        float hnn = acc[mt][3][r] + b_hn;
        float rg = 1.f / (1.f + __expf(-rs));
        float zg = 1.f / (1.f + __expf(-zs));
        float a = inn + rg * hnn;
        a = fminf(fmaxf(a, -15.f), 15.f);
        float e2 = __expf(2.f * a);
        float nn = (e2 - 1.f) / (e2 + 1.f);
        float hold = h[(size_t)gn * D + o];
        h[(size_t)gn * D + o] = (1.f - zg) * nn + zg * hold;
      }
    }
  }
}

// ---------------- predictor: score_e = [h_src | h_dst] . pW + pb ----------------
__global__ __launch_bounds__(256) void k_pred(const float* __restrict__ h,
                                              const int* __restrict__ src,
                                              const int* __restrict__ dst,
                                              const float* __restrict__ pW,
                                              const float* __restrict__ pb,
                                              float* __restrict__ out) {
  int wave = threadIdx.x >> 6, lane = threadIdx.x & 63;
  int e = blockIdx.x * 4 + wave;
  int s = src[e], d2 = dst[e];
  float v = h[(size_t)s * D + lane] * pW[lane] + h[(size_t)d2 * D + lane] * pW[64 + lane];
#pragma unroll
  for (int off = 32; off >= 1; off >>= 1) v += __shfl_xor(v, off, 64);
  if (lane == 0) out[e] = v + pb[0];
}

extern "C" void kernel_launch(void* const* d_in, const int* in_sizes, int n_in,
                              void* d_out, int out_size, void* d_ws, size_t ws_size,
                              hipStream_t stream) {
  const float* node_feats = (const float*)d_in[0];
  const float* edge_feats = (const float*)d_in[1];
  const int* src = (const int*)d_in[2];
  const int* dst = (const int*)d_in[3];
  const float* proj_W = (const float*)d_in[4];
  const float* proj_b = (const float*)d_in[5];
  const float* en_W1 = (const float*)d_in[6];
  const float* en_b1 = (const float*)d_in[7];
  const float* en_W2 = (const float*)d_in[8];
  const float* en_b2 = (const float*)d_in[9];
  const float* conv_b = (const float*)d_in[10];
  const float* gru_Wih = (const float*)d_in[11];
  const float* gru_Whh = (const float*)d_in[12];
  const float* gru_bih = (const float*)d_in[13];
  const float* gru_bhh = (const float*)d_in[14];
  const float* pred_W = (const float*)d_in[15];
  const float* pred_b = (const float*)d_in[16];

  char* ws = (char*)d_ws;
  size_t off = 0;
  auto walloc = [&](size_t bytes) -> void* {
    void* p = ws + off;
    off = (off + bytes + 255) & ~(size_t)255;
    return p;
  };
  float* h = (float*)walloc((size_t)NV * D * 4);
  float* neigh = (float*)walloc((size_t)NV * D * 4);
  __hip_bfloat16* t_bf = (__hip_bfloat16*)walloc((size_t)NE * EHID * 2);
  __hip_bfloat16* w2_bf = (__hip_bfloat16*)walloc((size_t)D * D * EHID * 2);
  __hip_bfloat16* b2t = (__hip_bfloat16*)walloc((size_t)D * D * 2);
  __hip_bfloat16* Bhi = (__hip_bfloat16*)walloc((size_t)256 * 128 * 2);
  __hip_bfloat16* Blo = (__hip_bfloat16*)walloc((size_t)256 * 128 * 2);

  k_proj<<<NV / 4, 256, 0, stream>>>(node_feats, proj_W, proj_b, h, neigh);
  k_edge1<<<NE / 2, 256, 0, stream>>>(edge_feats, en_W1, en_b1, t_bf);
  k_cvt_w2<<<(D * D * EHID + 255) / 256, 256, 0, stream>>>(en_W2, w2_bf);
  k_b2t<<<(D * D + 255) / 256, 256, 0, stream>>>(en_b2, b2t);
  k_build_b<<<128, 256, 0, stream>>>(gru_Wih, gru_Whh, Bhi, Blo);
  for (int s = 0; s < NSTEPS; ++s) {
    k_msg<<<256, 512, 0, stream>>>(h, t_bf, w2_bf, b2t, src, dst, neigh);
    k_gru<<<(NV + 63) / 64, 256, 0, stream>>>(neigh, h, Bhi, Blo, conv_b, gru_bih, gru_bhh);
  }
  k_pred<<<NE / 4, 256, 0, stream>>>(h, src, dst, pred_W, pred_b, (float*)d_out);
}